// Round 6
// baseline (1027.613 us; speedup 1.0000x reference)
//
#include <hip/hip_runtime.h>
#include <stdint.h>

#define N_TOK 8192
#define DDIM 2048
#define IDIM 6144
#define NEXP 8
#define RLORA 32
#define NCHUNK 64
#define CHUNK 128

typedef __attribute__((ext_vector_type(8))) short short8;
typedef __attribute__((ext_vector_type(4))) float floatx4;
typedef __attribute__((ext_vector_type(4))) unsigned short ushortx4;

__device__ __forceinline__ unsigned short f2bf(float f) {
  union { float f; unsigned u; } v; v.f = f;
  unsigned u = v.u;
  unsigned r = (u + 0x7fffu + ((u >> 16) & 1u)) >> 16;
  return (unsigned short)r;
}

__device__ __forceinline__ void gload_lds16(const void* g, void* l) {
  __builtin_amdgcn_global_load_lds(
      (const __attribute__((address_space(1))) void*)g,
      (__attribute__((address_space(3))) void*)l, 16, 0, 0);
}

// ---------------- router: logits (fp32, original order) + top-1 idx ----------------
__global__ __launch_bounds__(256) void router_kernel(
    const float* __restrict__ x, const float* __restrict__ rw,
    float* __restrict__ logits_out, int* __restrict__ idx) {
  int wave = threadIdx.x >> 6, lane = threadIdx.x & 63;
  int n = blockIdx.x * 4 + wave;
  const float* xr = x + (size_t)n * DDIM;
  float acc[NEXP];
#pragma unroll
  for (int e = 0; e < NEXP; e++) acc[e] = 0.f;
#pragma unroll
  for (int j = 0; j < 8; j++) {
    int d = j * 256 + lane * 4;
    floatx4 v = *(const floatx4*)(xr + d);
    const float* rwd = rw + (size_t)d * NEXP;
#pragma unroll
    for (int t = 0; t < 4; t++) {
      float xv = v[t];
      const float* rr = rwd + t * NEXP;
#pragma unroll
      for (int e = 0; e < NEXP; e++) acc[e] += xv * rr[e];
    }
  }
#pragma unroll
  for (int off = 32; off > 0; off >>= 1) {
#pragma unroll
    for (int e = 0; e < NEXP; e++) acc[e] += __shfl_xor(acc[e], off, 64);
  }
  if (lane == 0) {
    float best = acc[0]; int bi = 0;
#pragma unroll
    for (int e = 1; e < NEXP; e++)
      if (acc[e] > best) { best = acc[e]; bi = e; }
    idx[n] = bi;
#pragma unroll
    for (int e = 0; e < NEXP; e++) logits_out[(size_t)n * NEXP + e] = acc[e];
  }
}

// ---------------- sort step 1: per-chunk expert counts ----------------
__global__ __launch_bounds__(128) void count_kernel(
    const int* __restrict__ idx, int* __restrict__ cnt) {
  __shared__ int h[NEXP];
  if (threadIdx.x < NEXP) h[threadIdx.x] = 0;
  __syncthreads();
  int n = blockIdx.x * CHUNK + threadIdx.x;
  atomicAdd(&h[idx[n]], 1);
  __syncthreads();
  if (threadIdx.x < NEXP) cnt[blockIdx.x * NEXP + threadIdx.x] = h[threadIdx.x];
}

// ---------------- sort step 2: exclusive scan (expert-major) ----------------
__global__ __launch_bounds__(64) void scan_kernel(
    const int* __restrict__ cnt, int* __restrict__ off) {
  __shared__ int tot[NEXP], base[NEXP];
  int t = threadIdx.x;
  if (t < NEXP) {
    int s = 0;
    for (int c = 0; c < NCHUNK; c++) s += cnt[c * NEXP + t];
    tot[t] = s;
  }
  __syncthreads();
  if (t == 0) {
    int run = 0;
    for (int e = 0; e < NEXP; e++) { base[e] = run; run += tot[e]; }
  }
  __syncthreads();
  if (t < NEXP) {
    int run = base[t];
    for (int c = 0; c < NCHUNK; c++) { off[c * NEXP + t] = run; run += cnt[c * NEXP + t]; }
  }
}

// ---------------- sort step 3: ranks -> permutation ----------------
__global__ __launch_bounds__(64) void rank_kernel(
    const int* __restrict__ idx, const int* __restrict__ off,
    int* __restrict__ sortpos, int* __restrict__ orig, int* __restrict__ eidx) {
  if (threadIdx.x != 0) return;
  int c = blockIdx.x;
  int lc[NEXP];
#pragma unroll
  for (int e = 0; e < NEXP; e++) lc[e] = 0;
  for (int t = 0; t < CHUNK; t++) {
    int n = c * CHUNK + t;
    int e = idx[n];
    int dst = off[c * NEXP + e] + lc[e]++;
    sortpos[n] = dst;
    orig[dst] = n;
    eidx[dst] = e;
  }
}

// ---------------- permuted x -> bf16 (row-coalesced) ----------------
__global__ __launch_bounds__(256) void permute_x_kernel(
    const float* __restrict__ x, const int* __restrict__ sortpos,
    unsigned short* __restrict__ xb) {
  int wave = threadIdx.x >> 6, lane = threadIdx.x & 63;
  int n = blockIdx.x * 4 + wave;
  int dst = sortpos[n];
  const float* xr = x + (size_t)n * DDIM;
  unsigned short* xbr = xb + (size_t)dst * DDIM;
#pragma unroll
  for (int j = 0; j < 8; j++) {
    int d = j * 256 + lane * 4;
    floatx4 v = *(const floatx4*)(xr + d);
    ushortx4 s;
    s[0] = f2bf(v[0]); s[1] = f2bf(v[1]); s[2] = f2bf(v[2]); s[3] = f2bf(v[3]);
    *(ushortx4*)(xbr + d) = s;
  }
}

// ---------------- fp32 [Rr][Cc] -> bf16 [Cc][Rr] transpose (for Wd) ----------------
__global__ __launch_bounds__(256) void transpose_w_kernel(
    const float* __restrict__ in, unsigned short* __restrict__ out, int Rr, int Cc) {
  __shared__ float lds[32][33];
  int r0 = blockIdx.y * 32, c0 = blockIdx.x * 32;
  int tx = threadIdx.x & 31, ty = threadIdx.x >> 5;
#pragma unroll
  for (int k = 0; k < 4; k++) {
    int r = ty + k * 8;
    lds[r][tx] = in[(size_t)(r0 + r) * Cc + c0 + tx];
  }
  __syncthreads();
#pragma unroll
  for (int k = 0; k < 4; k++) {
    int cc = ty + k * 8;
    out[(size_t)(c0 + cc) * Rr + r0 + tx] = f2bf(lds[tx][cc]);
  }
}

// ---------------- Wg/Wu [D][I] fp32 -> interleaved bf16 wint[2i+w][D] ----------------
__global__ __launch_bounds__(256) void transpose_wint_kernel(
    const float* __restrict__ Wg, const float* __restrict__ Wu,
    unsigned short* __restrict__ wint) {
  __shared__ float lds[32][33];
  int r0 = blockIdx.y * 32, c0 = blockIdx.x * 32;   // r over D, c over I
  const float* in = blockIdx.z ? Wu : Wg;
  int w = blockIdx.z;
  int tx = threadIdx.x & 31, ty = threadIdx.x >> 5;
#pragma unroll
  for (int k = 0; k < 4; k++) {
    int r = ty + k * 8;
    lds[r][tx] = in[(size_t)(r0 + r) * IDIM + c0 + tx];
  }
  __syncthreads();
#pragma unroll
  for (int k = 0; k < 4; k++) {
    int cc = ty + k * 8;
    wint[(size_t)(2 * (c0 + cc) + w) * DDIM + r0 + tx] = f2bf(lds[tx][cc]);
  }
}

// ---------------- pack A_gate/A_up -> aat[512][2048] bf16 (row = h*256+e*32+r) ----------------
__global__ __launch_bounds__(256) void pack_a_kernel(
    const float* __restrict__ Ag, const float* __restrict__ Au,
    unsigned short* __restrict__ aat) {
  int o = blockIdx.x * 256 + threadIdx.x;    // [0, 2^20)
  int h = o >> 19;
  int oo = o & ((1 << 19) - 1);
  int c = oo >> 11, d = oo & 2047;           // c in [0,256)
  int e = c >> 5, r = c & 31;
  const float* src = h ? Au : Ag;
  float v = src[(e << 16) + (d << 5) + r];   // A[e][d][r]
  aat[(size_t)(h * 256 + c) * DDIM + d] = f2bf(v);
}

// ---------------- BL[e][2j+w][64] bf16: [Bg col | 0] / [0 | Bu col] ----------------
__global__ __launch_bounds__(256) void pack_bl_kernel(
    const float* __restrict__ Bg, const float* __restrict__ Bu,
    unsigned short* __restrict__ BL) {
  int o = (blockIdx.x * 256 + threadIdx.x) * 4;   // short index, total 8*12288*64
  int kk = o & 63;
  int t2 = o >> 6;
  int c = t2 % (2 * IDIM);
  int e = t2 / (2 * IDIM);
  int j = c >> 1, w = c & 1;
  ushortx4 s;
#pragma unroll
  for (int r = 0; r < 4; r++) {
    int k = kk + r;
    float v;
    if (w == 0) v = (k < 32) ? Bg[((size_t)e * RLORA + k) * IDIM + j] : 0.f;
    else        v = (k >= 32) ? Bu[((size_t)e * RLORA + (k - 32)) * IDIM + j] : 0.f;
    s[r] = f2bf(v);
  }
  *(ushortx4*)(BL + o) = s;
}

// ---------------- Tsel[8192][64]: per-token own-expert x@[A_gate|A_up] ----------------
__global__ __launch_bounds__(256) void gemm_tsel_kernel(
    const unsigned short* __restrict__ xb, const unsigned short* __restrict__ aat,
    const int* __restrict__ eidx, unsigned short* __restrict__ Tsel) {
  __shared__ __align__(16) unsigned short sA[4096], sB[2048];
  __shared__ int es_s[128];
  const int row0 = blockIdx.x * 128;
  const int tid = threadIdx.x;
  const int wave = tid >> 6, lane = tid & 63;
  const int wr = wave >> 1, wc = wave & 1;
  const int q = lane >> 4, m16 = lane & 15;
  if (tid < 128) es_s[tid] = eidx[row0 + tid];
  __syncthreads();
  const int emin = es_s[0], emax = es_s[127];
  int erow[4];
#pragma unroll
  for (int m = 0; m < 4; m++) erow[m] = es_s[wr * 64 + m * 16 + m16];
  floatx4 acc[8];
#pragma unroll
  for (int i = 0; i < 8; i++)
#pragma unroll
    for (int j = 0; j < 4; j++) acc[i][j] = 0.f;
  short8 zero;
#pragma unroll
  for (int i = 0; i < 8; i++) zero[i] = 0;
  for (int ee = emin; ee <= emax; ee++) {
    for (int k0 = 0; k0 < DDIM; k0 += 32) {
      __syncthreads();
#pragma unroll
      for (int rr = 0; rr < 2; rr++) {
        int e = tid * 8 + rr * 2048;
        int r = e >> 5, kk = e & 31;
        gload_lds16(xb + (size_t)(row0 + r) * DDIM + (k0 + kk), sA + e);
      }
      {
        int e2 = tid * 8;
        int c = e2 >> 5, kk = e2 & 31;
        int srow = (c < 32) ? (ee * 32 + c) : (256 + ee * 32 + (c - 32));
        gload_lds16(aat + (size_t)srow * DDIM + (k0 + kk), sB + e2);
      }
      __syncthreads();
      short8 a[4], b[2];
#pragma unroll
      for (int m = 0; m < 4; m++) {
        short8 av = *(const short8*)(sA + (wr * 64 + m * 16 + m16) * 32 + q * 8);
        a[m] = (erow[m] == ee) ? av : zero;
      }
#pragma unroll
      for (int n = 0; n < 2; n++)
        b[n] = *(const short8*)(sB + (wc * 32 + n * 16 + m16) * 32 + q * 8);
#pragma unroll
      for (int m = 0; m < 4; m++)
#pragma unroll
        for (int n = 0; n < 2; n++)
          acc[m * 2 + n] = __builtin_amdgcn_mfma_f32_16x16x32_bf16(a[m], b[n], acc[m * 2 + n], 0, 0, 0);
    }
  }
#pragma unroll
  for (int m = 0; m < 4; m++)
#pragma unroll
    for (int n = 0; n < 2; n++)
#pragma unroll
      for (int r = 0; r < 4; r++) {
        int grow = row0 + wr * 64 + m * 16 + q * 4 + r;
        int gcol = wc * 32 + n * 16 + m16;
        Tsel[(size_t)grow * 64 + gcol] = f2bf(acc[m * 2 + n][r]);
      }
}

// ---------------- shared 256x256 main loop: software-pipelined clusters ----------------
// Per K-tile kt, body = [barrier crossed] -> Y-MFMA(kt-1) from regs -> issue 12
// ds_reads(kt) + stage(kt+3) (reads execute in LDS pipe UNDER Y's MFMA) ->
// lgkm(4) -> X-MFMA(kt) -> lgkm(0) -> counted vmcnt -> barrier. aY + b-frags
// live across the barrier; b double-buffered (bE/bO, static via 2x unroll).
// WAR: every wave's reads retired (lgkm(0)) before the barrier preceding the
// stage that overwrites slot (kt+3)&3 = (kt-1)&3. vmcnt(8) retires tile kt+1
// before the barrier preceding its reads. Stages are global_* (vmcnt only).
__device__ __forceinline__ void mm256_main(const unsigned short* __restrict__ Aptr,
                                           const unsigned short* __restrict__ Bptr,
                                           int K, int row0, int col0,
                                           unsigned short* smem, floatx4* acc) {
  const int tid = threadIdx.x;
  const int lane = tid & 63, wave = tid >> 6;
  const int wm = wave >> 2, wn = wave & 3;
  const int q = lane >> 4, m16 = lane & 15;
  const int NT = K >> 5;

  int offA[8], offB[4];
#pragma unroll
  for (int m = 0; m < 8; m++) {
    int rw2 = wm * 128 + m * 16 + m16;
    offA[m] = rw2 * 32 + ((q ^ ((rw2 >> 1) & 3)) * 8);
  }
#pragma unroll
  for (int n = 0; n < 4; n++) {
    int c = wn * 64 + n * 16 + m16;
    offB[n] = 8192 + c * 32 + ((q ^ ((c >> 1) & 3)) * 8);
  }

  auto stageA = [&](int kt) {
    unsigned short* Ab = smem + (kt & 3) * 16384;
#pragma unroll
    for (int ch = 0; ch < 2; ch++) {
      int o = ch * 4096 + tid * 8;
      int rw2 = o >> 5, g = (o >> 3) & 3;
      int gs = g ^ ((rw2 >> 1) & 3);
      gload_lds16(Aptr + (size_t)(row0 + rw2) * K + kt * 32 + gs * 8, Ab + o);
    }
  };
  auto stageB = [&](int kt) {
    unsigned short* Bb = smem + (kt & 3) * 16384 + 8192;
#pragma unroll
    for (int ch = 0; ch < 2; ch++) {
      int o = ch * 4096 + tid * 8;
      int rw2 = o >> 5, g = (o >> 3) & 3;
      int gs = g ^ ((rw2 >> 1) & 3);
      gload_lds16(Bptr + (size_t)(col0 + rw2) * K + kt * 32 + gs * 8, Bb + o);
    }
  };

  short8 aX[4], aY[4], bE[4], bO[4];

#define GU_BODY(KT, BN, BP)                                                    \
  {                                                                            \
    const unsigned short* base = smem + ((KT) & 3) * 16384;                    \
    __builtin_amdgcn_s_setprio(1);                                             \
    _Pragma("unroll")                                                          \
    for (int m = 0; m < 4; m++)                                                \
      _Pragma("unroll")                                                        \
      for (int n = 0; n < 4; n++)                                              \
        acc[16 + m * 4 + n] = __builtin_amdgcn_mfma_f32_16x16x32_bf16(         \
            aY[m], BP[n], acc[16 + m * 4 + n], 0, 0, 0);                       \
    __builtin_amdgcn_s_setprio(0);                                             \
    _Pragma("unroll")                                                          \
    for (int m = 0; m < 4; m++) aX[m] = *(const short8*)(base + offA[m]);      \
    _Pragma("unroll")                                                          \
    for (int n = 0; n < 4; n++) BN[n] = *(const short8*)(base + offB[n]);      \
    __builtin_amdgcn_sched_barrier(0);                                         \
    _Pragma("unroll")                                                          \
    for (int m = 0; m < 4; m++) aY[m] = *(const short8*)(base + offA[4 + m]);  \
    if ((KT) + 3 < NT) { stageA((KT) + 3); stageB((KT) + 3); }                 \
    asm volatile("s_waitcnt lgkmcnt(4)" ::: "memory");                         \
    __builtin_amdgcn_sched_barrier(0);                                         \
    __builtin_amdgcn_s_setprio(1);                                             \
    _Pragma("unroll")                                                          \
    for (int m = 0; m < 4; m++)                                                \
      _Pragma("unroll")                                                        \
      for (int n = 0; n < 4; n++)                                              \
        acc[m * 4 + n] = __builtin_amdgcn_mfma_f32_16x16x32_bf16(              \
            aX[m], BN[n], acc[m * 4 + n], 0, 0, 0);                            \
    __builtin_amdgcn_s_setprio(0);                                             \
    asm volatile("s_waitcnt lgkmcnt(0)" ::: "memory");                         \
    __builtin_amdgcn_sched_barrier(0);                                         \
    if ((KT) < NT - 3)       asm volatile("s_waitcnt vmcnt(8)" ::: "memory");  \
    else if ((KT) == NT - 3) asm volatile("s_waitcnt vmcnt(4)" ::: "memory");  \
    else if ((KT) == NT - 2) asm volatile("s_waitcnt vmcnt(0)" ::: "memory");  \
    __builtin_amdgcn_s_barrier();                                              \
  }

  // prologue: stage tiles 0..2, then tile-0 X phase (loads aY/bE for Y(0))
  stageA(0); stageB(0); stageA(1); stageB(1); stageA(2); stageB(2);
  asm volatile("s_waitcnt vmcnt(8)" ::: "memory");
  __builtin_amdgcn_s_barrier();
  __builtin_amdgcn_sched_barrier(0);
  {
    const unsigned short* base = smem;
#pragma unroll
    for (int m = 0; m < 4; m++) aX[m] = *(const short8*)(base + offA[m]);
#pragma unroll
    for (int n = 0; n < 4; n++) bE[n] = *(const short8*)(base + offB[n]);
    __builtin_amdgcn_sched_barrier(0);
#pragma unroll
    for (int m = 0; m < 4; m++) aY[m] = *(const short8*)(base + offA[4 + m]);
    stageA(3); stageB(3);
    asm volatile("s_waitcnt lgkmcnt(4)" ::: "memory");
    __builtin_amdgcn_sched_barrier(0);
    __builtin_amdgcn_s_setprio(1);
#pragma unroll
    for (int m = 0; m < 4; m++)
#pragma unroll
      for (int n = 0; n < 4; n++)
        acc[m * 4 + n] = __builtin_amdgcn_mfma_f32_16x16x32_bf16(aX[m], bE[n], acc[m * 4 + n], 0, 0, 0);
    __builtin_amdgcn_s_setprio(0);
    asm volatile("s_waitcnt lgkmcnt(0)" ::: "memory");
    __builtin_amdgcn_sched_barrier(0);
    asm volatile("s_waitcnt vmcnt(8)" ::: "memory");
    __builtin_amdgcn_s_barrier();
  }
  // main loop: pairs keep b-buffer names static (rule #20)
  for (int kt = 1; kt + 1 < NT; kt += 2) {
    GU_BODY(kt, bO, bE);
    GU_BODY(kt + 1, bE, bO);
  }
  GU_BODY(NT - 1, bO, bE);   // NT even: kt=NT-1 odd -> bN=bO, bP=bE
  // final Y(NT-1)
  __builtin_amdgcn_s_setprio(1);
#pragma unroll
  for (int m = 0; m < 4; m++)
#pragma unroll
    for (int n = 0; n < 4; n++)
      acc[16 + m * 4 + n] = __builtin_amdgcn_mfma_f32_16x16x32_bf16(aY[m], bO[n], acc[16 + m * 4 + n], 0, 0, 0);
  __builtin_amdgcn_s_setprio(0);
#undef GU_BODY
}

// ---------------- fused gate+up GEMM: 256x256 interleaved tile ----------------
__global__ __launch_bounds__(512, 2) void gemm_gateup_kernel(
    const unsigned short* __restrict__ xb, const unsigned short* __restrict__ wint,
    const unsigned short* __restrict__ Tsel, const unsigned short* __restrict__ BL,
    const int* __restrict__ eidx, unsigned short* __restrict__ hbuf) {
  __shared__ __align__(16) unsigned short smem[65536];  // 128 KB

  // XCD swizzle: 1536 blocks = 8 xcd * 192; 2-col-tile subgroups x 32 row tiles.
  int lin = blockIdx.x;
  int xcd = lin & 7, slot = lin >> 3;      // slot [0,192)
  int grp = slot >> 6, r = slot & 63;      // grp 0..2
  int bx = xcd * 6 + grp * 2 + (r & 1);    // col tile [0,48)
  int by = r >> 1;                         // row tile [0,32)
  const int row0 = by * 256, col0 = bx * 256;

  const int tid = threadIdx.x;
  const int lane = tid & 63, wave = tid >> 6;
  const int wm = wave >> 2, wn = wave & 3;
  const int q = lane >> 4, m16 = lane & 15;

  floatx4 acc[32];
#pragma unroll
  for (int i = 0; i < 32; i++)
#pragma unroll
    for (int j = 0; j < 4; j++) acc[i][j] = 0.f;

  mm256_main(xb, wint, DDIM, row0, col0, smem, acc);

  // ---- LoRA epilogue (K=64 tiles, swizzle sel = row&7) ----
#pragma unroll
  for (int ch = 0; ch < 4; ch++) {
    int o = ch * 4096 + tid * 8;
    int rw2 = o >> 6, g = (o >> 3) & 7;
    int gs = g ^ (rw2 & 7);
    gload_lds16(Tsel + (size_t)(row0 + rw2) * 64 + gs * 8, smem + o);
  }
  int* es = (int*)(smem + 32768);
  if (tid < 64) gload_lds16(eidx + row0 + tid * 4, (void*)(es + tid * 4));
  asm volatile("s_waitcnt vmcnt(0)" ::: "memory");
  __builtin_amdgcn_s_barrier();
  __builtin_amdgcn_sched_barrier(0);

  const int emin = es[0], emax = es[255];
  int erow[8];
#pragma unroll
  for (int m = 0; m < 8; m++) erow[m] = es[wm * 128 + m * 16 + m16];

  auto stage_bl = [&](int ee) {
#pragma unroll
    for (int ch = 0; ch < 4; ch++) {
      int o = ch * 4096 + tid * 8;
      int c = o >> 6, g = (o >> 3) & 7;
      int gs = g ^ (c & 7);
      gload_lds16(BL + ((size_t)ee * (2 * IDIM) + col0 + c) * 64 + gs * 8, smem + 16384 + o);
    }
  };
  stage_bl(emin);
  asm volatile("s_waitcnt vmcnt(0)" ::: "memory");
  __builtin_amdgcn_s_barrier();
  __builtin_amdgcn_sched_barrier(0);

  short8 zero;
#pragma unroll
  for (int i = 0; i < 8; i++) zero[i] = 0;

  for (int ee = emin; ee <= emax; ee++) {
    short8 bl[4][2];
#pragma unroll
    for (int n = 0; n < 4; n++) {
      int c = wn * 64 + n * 16 + m16;
#pragma unroll
      for (int kk = 0; kk < 2; kk++) {
        int gg = (kk * 4 + q) ^ (c & 7);
        bl[n][kk] = *(const short8*)(smem + 16384 + c * 64 + gg * 8);
      }
    }
#pragma unroll
    for (int m = 0; m < 8; m++) {
      int rw2 = wm * 128 + m * 16 + m16;
      short8 tgm[2];
#pragma unroll
      for (int kk = 0; kk < 2; kk++) {
        int gg = (kk * 4 + q) ^ (rw2 & 7);
        short8 v = *(const short8*)(smem + rw2 * 64 + gg * 8);
        tgm[kk] = (erow[m] == ee) ? v : zero;
      }
#pragma unroll
      for (int n = 0; n < 4; n++)
#pragma unroll
        for (int kk = 0; kk < 2; kk++)
          acc[m * 4 + n] = __builtin_amdgcn_mfma_f32_16x16x32_bf16(tgm[kk], bl[n][kk], acc[m * 4 + n], 0, 0, 0);
    }
    if (ee < emax) {
      __builtin_amdgcn_s_barrier();    // all reads of BL retired
      stage_bl(ee + 1);
      asm volatile("s_waitcnt vmcnt(0)" ::: "memory");
      __builtin_amdgcn_s_barrier();
      __builtin_amdgcn_sched_barrier(0);
    }
  }

  // ---- SwiGLU in registers: pair gate(even m16)/up(odd m16) via shfl_xor(1) ----
#pragma unroll
  for (int m = 0; m < 8; m++)
#pragma unroll
    for (int n = 0; n < 4; n++)
#pragma unroll
      for (int rr2 = 0; rr2 < 4; rr2++) {
        float v = acc[m * 4 + n][rr2];
        float p = __shfl_xor(v, 1, 64);
        float g = (m16 & 1) ? p : v;
        float u = (m16 & 1) ? v : p;
        float h = g / (1.f + __expf(-g)) * u;
        if (!(m16 & 1)) {
          int grow = row0 + wm * 128 + m * 16 + q * 4 + rr2;
          int gi = (col0 + wn * 64 + n * 16 + m16) >> 1;
          hbuf[(size_t)grow * IDIM + gi] = f2bf(h);
        }
      }
}

// ---------------- down GEMM: same pipelined 256x256 structure ----------------
__global__ __launch_bounds__(512, 2) void gemm_down_kernel(
    const unsigned short* __restrict__ hb, const unsigned short* __restrict__ wdt,
    const int* __restrict__ orig, float* __restrict__ out) {
  __shared__ __align__(16) unsigned short smem[65536];
  // 256 blocks = 1/CU; each XCD owns one 256-col tile (B panel 3 MB, L2-resident)
  int lin = blockIdx.x;
  int bx = lin & 7, by = lin >> 3;         // col tile [0,8), row tile [0,32)
  const int row0 = by * 256, col0 = bx * 256;

  floatx4 acc[32];
#pragma unroll
  for (int i = 0; i < 32; i++)
#pragma unroll
    for (int j = 0; j < 4; j++) acc[i][j] = 0.f;

  mm256_main(hb, wdt, IDIM, row0, col0, smem, acc);

  const int tid = threadIdx.x;
  const int lane = tid & 63, wave = tid >> 6;
  const int wm = wave >> 2, wn = wave & 3;
  const int q = lane >> 4, m16 = lane & 15;
#pragma unroll
  for (int m = 0; m < 8; m++)
#pragma unroll
    for (int n = 0; n < 4; n++)
#pragma unroll
      for (int r = 0; r < 4; r++) {
        int grow = row0 + wm * 128 + m * 16 + q * 4 + r;
        int orow = orig[grow];
        int gcol = col0 + wn * 64 + n * 16 + m16;
        out[(size_t)orow * DDIM + gcol] = acc[m * 4 + n][r];
      }
}

extern "C" void kernel_launch(void* const* d_in, const int* in_sizes, int n_in,
                              void* d_out, int out_size, void* d_ws, size_t ws_size,
                              hipStream_t stream) {
  const float* x  = (const float*)d_in[0];
  const float* rw = (const float*)d_in[1];
  const float* Ag = (const float*)d_in[2];
  const float* Bg = (const float*)d_in[3];
  const float* Au = (const float*)d_in[4];
  const float* Bu = (const float*)d_in[5];
  const float* Wg = (const float*)d_in[6];
  const float* Wu = (const float*)d_in[7];
  const float* Wd = (const float*)d_in[8];
  float* out = (float*)d_out;
  float* logits = out + (size_t)N_TOK * DDIM;

  char* ws = (char*)d_ws;
  size_t off = 0;
  auto alloc = [&](size_t bytes) {
    char* p = ws + off;
    off += (bytes + 255) & ~(size_t)255;
    return p;
  };
  unsigned short* xb  = (unsigned short*)alloc((size_t)N_TOK * DDIM * 2);
  unsigned short* wint= (unsigned short*)alloc((size_t)2 * IDIM * DDIM * 2);
  unsigned short* wdt = (unsigned short*)alloc((size_t)DDIM * IDIM * 2);
  unsigned short* aat = (unsigned short*)alloc((size_t)512 * DDIM * 2);
  unsigned short* BL  = (unsigned short*)alloc((size_t)NEXP * 2 * IDIM * 64 * 2);
  unsigned short* Tsel= (unsigned short*)alloc((size_t)N_TOK * 64 * 2);
  unsigned short* hbuf= (unsigned short*)alloc((size_t)N_TOK * IDIM * 2);
  int* idx     = (int*)alloc((size_t)N_TOK * 4);
  int* sortpos = (int*)alloc((size_t)N_TOK * 4);
  int* orig    = (int*)alloc((size_t)N_TOK * 4);
  int* eidx    = (int*)alloc((size_t)N_TOK * 4);
  int* cnt     = (int*)alloc((size_t)NCHUNK * NEXP * 4);
  int* offb    = (int*)alloc((size_t)NCHUNK * NEXP * 4);

  router_kernel<<<N_TOK / 4, 256, 0, stream>>>(x, rw, logits, idx);
  count_kernel<<<NCHUNK, 128, 0, stream>>>(idx, cnt);
  scan_kernel<<<1, 64, 0, stream>>>(cnt, offb);
  rank_kernel<<<NCHUNK, 64, 0, stream>>>(idx, offb, sortpos, orig, eidx);
  permute_x_kernel<<<N_TOK / 4, 256, 0, stream>>>(x, sortpos, xb);
  transpose_w_kernel<<<dim3(DDIM / 32, IDIM / 32), 256, 0, stream>>>(Wd, wdt, IDIM, DDIM);
  transpose_wint_kernel<<<dim3(IDIM / 32, DDIM / 32, 2), 256, 0, stream>>>(Wg, Wu, wint);
  pack_a_kernel<<<4096, 256, 0, stream>>>(Ag, Au, aat);
  pack_bl_kernel<<<(NEXP * 2 * IDIM * 64) / 1024, 256, 0, stream>>>(Bg, Bu, BL);
  gemm_tsel_kernel<<<N_TOK / 128, 256, 0, stream>>>(xb, aat, eidx, Tsel);
  gemm_gateup_kernel<<<(N_TOK / 256) * (2 * IDIM / 256), 512, 0, stream>>>(
      xb, wint, Tsel, BL, eidx, hbuf);
  gemm_down_kernel<<<256, 512, 0, stream>>>(hbuf, wdt, orig, out);
}